// Round 8
// baseline (465.582 us; speedup 1.0000x reference)
//
#include <hip/hip_runtime.h>
#include <stdint.h>
#include <math.h>

#define NTOK 4096
#define DIN  768
#define DSAE 32768
#define TOPK 64
#define CAP  1024
#define ZCOEF 0.045f
#define BAND 0.008f
#define BANDCAP 65536
#define BMAX 64

#define GBM 128
#define GBN 256
#define GBK 32
#define NT  (DIN / GBK)      // 24 k-steps
#define SLOT 24576           // 8KB A + 16KB B per ring slot
#define SEGC 24              // per-row per-block candidate cap

typedef float f32x4 __attribute__((ext_vector_type(4)));
typedef short short8 __attribute__((ext_vector_type(8)));

__device__ __forceinline__ ushort f2bf(float f) {
  uint32_t u = __float_as_uint(f);
  return (ushort)((u + 0x7fffu + ((u >> 16) & 1u)) >> 16);
}
__device__ __forceinline__ int swz(int o) { return o ^ (((o >> 7) & 3) << 4); }

// ---------------- K_pre: fused convT (blocks 0..6143) + prepA (blocks 6144..10239) ----------------
__global__ __launch_bounds__(256) void k_pre(const float* __restrict__ x,
                                             const float* __restrict__ b_dec,
                                             float* __restrict__ xm,
                                             ushort* __restrict__ Ah,
                                             float* __restrict__ tau,
                                             int* __restrict__ cnt,
                                             int* __restrict__ band_cnt,
                                             const float* __restrict__ W,
                                             float* __restrict__ Wt,
                                             ushort* __restrict__ Bth,
                                             int doWt) {
  __shared__ float Lf[128][33];
  __shared__ float red[4];
  const int bid = blockIdx.x;
  const int t = threadIdx.x;

  if (bid < (DIN / 32) * (DSAE / 128)) {
    // ---- convT part: Wt[n][k] = W_enc[k][n] fp32 (gated) + Bth bf16 ----
    const int bk = bid % (DIN / 32);
    const int bn = bid / (DIN / 32);
#pragma unroll
    for (int q = 0; q < 4; ++q) {
      const int idx = q * 256 + t;
      const int k = idx >> 5;
      const int n4 = (idx & 31) * 4;
      const float4 w = *(const float4*)(W + (size_t)(bk * 32 + k) * DSAE + (size_t)bn * 128 + n4);
      Lf[n4 + 0][k] = w.x;
      Lf[n4 + 1][k] = w.y;
      Lf[n4 + 2][k] = w.z;
      Lf[n4 + 3][k] = w.w;
    }
    __syncthreads();
#pragma unroll
    for (int q = 0; q < 4; ++q) {
      const int idx = q * 256 + t;
      const int n = idx >> 3;
      const int k4 = (idx & 7) * 4;
      float4 v;
      v.x = Lf[n][k4 + 0]; v.y = Lf[n][k4 + 1]; v.z = Lf[n][k4 + 2]; v.w = Lf[n][k4 + 3];
      const size_t ob = (size_t)(bn * 128 + n) * DIN + bk * 32 + k4;
      if (doWt) *(float4*)(Wt + ob) = v;
      ushort4 hh;
      hh.x = f2bf(v.x); hh.y = f2bf(v.y); hh.z = f2bf(v.z); hh.w = f2bf(v.w);
      *(ushort4*)(Bth + ob) = hh;
    }
  } else {
    // ---- prepA part: xm = x - b_dec (fp32 + bf16), tau, zero counters ----
    const int row = bid - (DIN / 32) * (DSAE / 128);
    float ss = 0.f;
    if (t < 192) {
      const float4 xv = *(const float4*)(x + (size_t)row * DIN + t * 4);
      const float4 bd = *(const float4*)(b_dec + t * 4);
      const float a0 = xv.x - bd.x, a1 = xv.y - bd.y, a2 = xv.z - bd.z, a3 = xv.w - bd.w;
      float4 m4;
      m4.x = a0; m4.y = a1; m4.z = a2; m4.w = a3;
      *(float4*)(xm + (size_t)row * DIN + t * 4) = m4;
      ushort4 h;
      h.x = f2bf(a0); h.y = f2bf(a1); h.z = f2bf(a2); h.w = f2bf(a3);
      *(ushort4*)(Ah + (size_t)row * DIN + t * 4) = h;
      ss = a0 * a0 + a1 * a1 + a2 * a2 + a3 * a3;
    }
#pragma unroll
    for (int o = 32; o > 0; o >>= 1) ss += __shfl_down(ss, o, 64);
    const int lane = t & 63, wid = t >> 6;
    if (lane == 0) red[wid] = ss;
    __syncthreads();
    if (t == 0) {
      tau[row] = ZCOEF * sqrtf(red[0] + red[1] + red[2] + red[3]);
      cnt[row] = 0;
      if (row == 0) band_cnt[0] = 0;
    }
  }
}

// ---------------- K1: bf16 MFMA GEMM, 3-slot ring + counted vmcnt + raw barrier ----------------
// R5-proven schedule; change: 4 waves x (64x128 out) per block -> reads/MFMA 0.5 -> 0.375
#define GLD(srcp, dstp) __builtin_amdgcn_global_load_lds( \
    (const __attribute__((address_space(1))) void*)(srcp), \
    (__attribute__((address_space(3))) void*)(dstp), 16, 0, 0)

__global__ __launch_bounds__(256, 2) void k_gemm_mfma(const ushort* __restrict__ Ah,
                                                      const ushort* __restrict__ Bth,
                                                      const float* __restrict__ b_enc,
                                                      const float* __restrict__ tau,
                                                      int* __restrict__ cnt,
                                                      float* __restrict__ cand_v,
                                                      int* __restrict__ cand_i) {
  __shared__ __align__(16) char smem[3 * SLOT];  // 72 KB ring: per slot 8KB A + 16KB B

  const int bid = blockIdx.x;
  const int xcd = bid & 7;
  const int i = bid >> 3;       // 0..511
  const int j = i & 15;
  const int st = i >> 4;        // 0..31
  const int bmg = st >> 3;      // 0..3
  const int bng = st & 7;       // 0..7
  const int bm = bmg * 8 + (j >> 1);             // 0..31
  const int bn = xcd * 16 + bng * 2 + (j & 1);   // 0..127

  const int t = threadIdx.x;
  const int lane = t & 63, wid = t >> 6;
  const int wr = wid >> 1, wc = wid & 1;     // 2 x 2 waves, each 64x128 out
  const int fr = lane & 15, fg = lane >> 4;

  f32x4 acc[4][8];
#pragma unroll
  for (int m = 0; m < 4; ++m)
#pragma unroll
    for (int n = 0; n < 8; ++n) acc[m][n] = (f32x4)0.f;

  // staging: 256 threads x 6 loads of 16B = 24 KB (A 8KB: 2 loads, B 16KB: 4 loads)
  const int oA0 = t * 16, oA1 = t * 16 + 4096;
  const int LA0 = swz(oA0), LA1 = swz(oA1);
  const int rA0 = LA0 >> 6, eA0 = (LA0 & 63) >> 1;
  const int rA1 = LA1 >> 6, eA1 = (LA1 & 63) >> 1;
  int rB[4], eB[4], oB[4];
#pragma unroll
  for (int q = 0; q < 4; ++q) {
    oB[q] = t * 16 + q * 4096;
    const int LB = swz(oB[q]);
    rB[q] = LB >> 6;
    eB[q] = (LB & 63) >> 1;
  }

  const size_t aRow = (size_t)bm * GBM;
  const size_t bRow = (size_t)bn * GBN;

  auto stage = [&](int slot, int kt) {
    const int k0 = kt * GBK;
    char* sA = smem + slot * SLOT;
    char* sB = sA + 8192;
    GLD(Ah + (aRow + rA0) * DIN + k0 + eA0, sA + oA0);
    GLD(Ah + (aRow + rA1) * DIN + k0 + eA1, sA + oA1);
#pragma unroll
    for (int q = 0; q < 4; ++q)
      GLD(Bth + (bRow + rB[q]) * DIN + k0 + eB[q], sB + oB[q]);
  };

  stage(0, 0);
  stage(1, 1);

  for (int kt = 0; kt < NT; ++kt) {
    // wait only for tile kt's 6 loads; tile kt+1's 6 stay in flight across the barrier
    if (kt < NT - 1) {
      asm volatile("s_waitcnt vmcnt(6)" ::: "memory");
    } else {
      asm volatile("s_waitcnt vmcnt(0)" ::: "memory");
    }
    __builtin_amdgcn_s_barrier();
    if (kt + 2 < NT) stage((kt + 2) % 3, kt + 2);

    const char* sA = smem + (kt % 3) * SLOT;
    const char* sB = sA + 8192;
    short8 ah[4], bh[8];
#pragma unroll
    for (int m = 0; m < 4; ++m) {
      const int L = ((wr * 64 + m * 16 + fr) << 6) | (fg << 4);
      ah[m] = *(const short8*)(sA + swz(L));
    }
#pragma unroll
    for (int n = 0; n < 8; ++n) {
      const int L = ((wc * 128 + n * 16 + fr) << 6) | (fg << 4);
      bh[n] = *(const short8*)(sB + swz(L));
    }
#pragma unroll
    for (int m = 0; m < 4; ++m)
#pragma unroll
      for (int n = 0; n < 8; ++n)
        acc[m][n] = __builtin_amdgcn_mfma_f32_16x16x32_bf16(ah[m], bh[n], acc[m][n], 0, 0, 0);
  }

  // -------- epilogue: LDS-aggregated candidate append --------
  __syncthreads();
  uint2* seg = (uint2*)smem;                   // [128][SEGC] (24 KB)
  int* lcnt = (int*)(smem + 128 * SEGC * 8);   // 128 ints
  if (t < 128) lcnt[t] = 0;
  __syncthreads();

  const int rbase = bm * GBM;
#pragma unroll
  for (int m = 0; m < 4; ++m) {
#pragma unroll
    for (int jj = 0; jj < 4; ++jj) {
      const int row_l = wr * 64 + m * 16 + fg * 4 + jj;
      const float trow = tau[rbase + row_l];
#pragma unroll
      for (int n = 0; n < 8; ++n) {
        const int col = bn * GBN + wc * 128 + n * 16 + fr;
        const float v = acc[m][n][jj] + b_enc[col];
        if (v > trow) {
          const int sl = atomicAdd(&lcnt[row_l], 1);
          if (sl < SEGC) seg[row_l * SEGC + sl] = make_uint2(__float_as_uint(v), (unsigned)col);
        }
      }
    }
  }
  __syncthreads();
  if (t < 128) {
    const int c = min(lcnt[t], SEGC);
    if (c > 0) {
      const int base = atomicAdd(&cnt[rbase + t], c);
      for (int s2 = 0; s2 < c; ++s2) {
        const int pos = base + s2;
        if (pos < CAP) {
          const uint2 e = seg[t * SEGC + s2];
          cand_v[(size_t)(rbase + t) * CAP + pos] = __uint_as_float(e.x);
          cand_i[(size_t)(rbase + t) * CAP + pos] = (int)e.y;
        }
      }
    }
  }
}

// ---------------- K_selref: fused band + refine + select + decode (fast path) ----------------
__global__ __launch_bounds__(256) void k_selref(const int* __restrict__ cnt,
                                                const float* __restrict__ cand_v,
                                                const int* __restrict__ cand_i,
                                                const float* __restrict__ xm,
                                                const float* __restrict__ Wt,
                                                const float* __restrict__ b_enc,
                                                const float* __restrict__ W_dec,
                                                const float* __restrict__ b_dec,
                                                float* __restrict__ out) {
  const int row = blockIdx.x;
  const int tid = threadIdx.x;
  const int lane = tid & 63, wid = tid >> 6;
  const int c = min(cnt[row], CAP);

  __shared__ unsigned su[CAP];
  __shared__ float sv[CAP];
  __shared__ float xr[DIN];
  __shared__ int redI[4];
  __shared__ int woff[4];
  __shared__ int basev;
  __shared__ int nband;
  __shared__ int bandl[BMAX];
  __shared__ float tv[TOPK];
  __shared__ int ti[TOPK];

  const float* cvr = cand_v + (size_t)row * CAP;
  const int* cir = cand_i + (size_t)row * CAP;
  for (int s = tid; s < c; s += 256) {
    const float v = cvr[s];
    sv[s] = v;
    su[s] = __float_as_uint(v);
  }
  xr[tid] = xm[(size_t)row * DIN + tid];
  xr[tid + 256] = xm[(size_t)row * DIN + tid + 256];
  xr[tid + 512] = xm[(size_t)row * DIN + tid + 512];
  if (tid == 0) nband = 0;
  __syncthreads();

  // radix pass 1: approx 64th-largest (on GEMM values)
  unsigned T = 0u;
  for (int b = 30; b >= 0; --b) {
    const unsigned Tt = T | (1u << b);
    int cg = 0;
    for (int s = tid; s < c; s += 256) cg += (su[s] >= Tt) ? 1 : 0;
#pragma unroll
    for (int o = 32; o > 0; o >>= 1) cg += __shfl_down(cg, o, 64);
    if (lane == 0) redI[wid] = cg;
    __syncthreads();
    const int tot = redI[0] + redI[1] + redI[2] + redI[3];
    if (tot >= TOPK) T = Tt;
    __syncthreads();
  }
  const float Ta = __uint_as_float(T);

  // collect band entries
  for (int s = tid; s < c; s += 256) {
    const float v = sv[s];
    if (v >= Ta - BAND && v <= Ta + BAND) {
      const int p = atomicAdd(&nband, 1);
      if (p < BMAX) bandl[p] = s;
    }
  }
  __syncthreads();
  const int nb = min(nband, BMAX);

  // refine: wave per entry, same arithmetic as R4-R7 k_refineT
  for (int e = wid; e < nb; e += 4) {
    const int s = bandl[e];
    const int col = cir[s];
    const float* wrow = Wt + (size_t)col * DIN;
    float acc = 0.f;
#pragma unroll
    for (int jj = 0; jj < 3; ++jj) {
      const float4 a = *(const float4*)&xr[lane * 4 + jj * 256];
      const float4 w = *(const float4*)(wrow + lane * 4 + jj * 256);
      acc = fmaf(a.x, w.x, acc);
      acc = fmaf(a.y, w.y, acc);
      acc = fmaf(a.z, w.z, acc);
      acc = fmaf(a.w, w.w, acc);
    }
#pragma unroll
    for (int o = 32; o > 0; o >>= 1) acc += __shfl_down(acc, o, 64);
    if (lane == 0) {
      const float nv = acc + b_enc[col];
      sv[s] = nv;
      su[s] = __float_as_uint(nv);
    }
  }
  __syncthreads();

  // radix pass 2: exact 64th-largest on corrected values
  T = 0u;
  for (int b = 30; b >= 0; --b) {
    const unsigned Tt = T | (1u << b);
    int cg = 0;
    for (int s = tid; s < c; s += 256) cg += (su[s] >= Tt) ? 1 : 0;
#pragma unroll
    for (int o = 32; o > 0; o >>= 1) cg += __shfl_down(cg, o, 64);
    if (lane == 0) redI[wid] = cg;
    __syncthreads();
    const int tot = redI[0] + redI[1] + redI[2] + redI[3];
    if (tot >= TOPK) T = Tt;
    __syncthreads();
  }

  if (tid == 0) basev = 0;
  __syncthreads();
  for (int s0 = 0; s0 < c; s0 += 256) {
    const int s = s0 + tid;
    const bool take = (s < c) && (su[s] > T);
    const unsigned long long m = __ballot(take);
    const int wsum = __popcll(m);
    const int wpre = __popcll(m & ((1ull << lane) - 1ull));
    if (lane == 0) woff[wid] = wsum;
    __syncthreads();
    int pre = 0;
    for (int w = 0; w < wid; ++w) pre += woff[w];
    const int tot = woff[0] + woff[1] + woff[2] + woff[3];
    if (take) {
      const int p = basev + pre + wpre;
      tv[p] = sv[s];
      ti[p] = cir[s];
    }
    __syncthreads();
    if (tid == 0) basev += tot;
    __syncthreads();
  }
  for (int s0 = 0; s0 < c; s0 += 256) {
    const int s = s0 + tid;
    const bool take = (s < c) && (su[s] == T);
    const unsigned long long m = __ballot(take);
    const int wsum = __popcll(m);
    const int wpre = __popcll(m & ((1ull << lane) - 1ull));
    if (lane == 0) woff[wid] = wsum;
    __syncthreads();
    int pre = 0;
    for (int w = 0; w < wid; ++w) pre += woff[w];
    const int tot = woff[0] + woff[1] + woff[2] + woff[3];
    if (take) {
      const int p = basev + pre + wpre;
      if (p < TOPK) {
        tv[p] = sv[s];
        ti[p] = cir[s];
      }
    }
    __syncthreads();
    if (tid == 0) basev += tot;
    __syncthreads();
  }

  for (int ksz = 2; ksz <= TOPK; ksz <<= 1) {
    for (int js = ksz >> 1; js > 0; js >>= 1) {
      if (tid < TOPK) {
        const int partner = tid ^ js;
        if (partner > tid) {
          const bool up = ((tid & ksz) == 0);
          const int a = ti[tid], b2 = ti[partner];
          if ((a > b2) == up) {
            ti[tid] = b2;
            ti[partner] = a;
            const float fa = tv[tid];
            tv[tid] = tv[partner];
            tv[partner] = fa;
          }
        }
      }
      __syncthreads();
    }
  }

  if (tid < 192) {
    const int d = tid * 4;
    float4 acc = *(const float4*)(b_dec + d);
#pragma unroll 8
    for (int k = 0; k < TOPK; ++k) {
      const float4 w = *(const float4*)(W_dec + (size_t)ti[k] * DIN + d);
      const float vk = tv[k];
      acc.x = fmaf(vk, w.x, acc.x);
      acc.y = fmaf(vk, w.y, acc.y);
      acc.z = fmaf(vk, w.z, acc.z);
      acc.w = fmaf(vk, w.w, acc.w);
    }
    *(float4*)(out + (size_t)row * DIN + d) = acc;
  }
}

// ================= fallback chain (ws too small for Wt) =================
__global__ __launch_bounds__(256) void k_band(const int* __restrict__ cnt,
                                              const float* __restrict__ cand_v,
                                              int* __restrict__ band_cnt,
                                              int* __restrict__ band_list) {
  const int row = blockIdx.x;
  const int tid = threadIdx.x;
  const int lane = tid & 63, wid = tid >> 6;
  const int c = min(cnt[row], CAP);
  __shared__ unsigned su[CAP];
  __shared__ int redI[4];
  const float* cvr = cand_v + (size_t)row * CAP;
  for (int s = tid; s < c; s += 256) su[s] = __float_as_uint(cvr[s]);
  __syncthreads();
  unsigned T = 0u;
  for (int b = 30; b >= 0; --b) {
    const unsigned Tt = T | (1u << b);
    int cg = 0;
    for (int s = tid; s < c; s += 256) cg += (su[s] >= Tt) ? 1 : 0;
#pragma unroll
    for (int o = 32; o > 0; o >>= 1) cg += __shfl_down(cg, o, 64);
    if (lane == 0) redI[wid] = cg;
    __syncthreads();
    const int tot = redI[0] + redI[1] + redI[2] + redI[3];
    if (tot >= TOPK) T = Tt;
    __syncthreads();
  }
  const float Tf = __uint_as_float(T);
  for (int s = tid; s < c; s += 256) {
    const float v = __uint_as_float(su[s]);
    if (v >= Tf - BAND && v <= Tf + BAND) {
      const int p = atomicAdd(band_cnt, 1);
      if (p < BANDCAP) band_list[p] = row * CAP + s;
    }
  }
}

__global__ __launch_bounds__(256) void k_refine(const int* __restrict__ band_cnt,
                                                const int* __restrict__ band_list,
                                                const float* __restrict__ xm,
                                                const float* __restrict__ W_enc,
                                                const float* __restrict__ b_enc,
                                                float* __restrict__ cand_v,
                                                const int* __restrict__ cand_i) {
  const int i = blockIdx.x * 256 + threadIdx.x;
  const int nb = min(band_cnt[0], BANDCAP);
  if (i >= nb) return;
  const int e = band_list[i];
  const int row = e >> 10;
  const int s = e & (CAP - 1);
  const int col = cand_i[(size_t)row * CAP + s];
  const float* xr = xm + (size_t)row * DIN;
  float acc = 0.f;
  for (int k = 0; k < DIN; ++k)
    acc = fmaf(xr[k], W_enc[(size_t)k * DSAE + col], acc);
  cand_v[(size_t)row * CAP + s] = acc + b_enc[col];
}

__global__ __launch_bounds__(256) void k_select(const int* __restrict__ cnt,
                                                const float* __restrict__ cand_v,
                                                const int* __restrict__ cand_i,
                                                float* __restrict__ top_v,
                                                int* __restrict__ top_i) {
  const int row = blockIdx.x;
  const int tid = threadIdx.x;
  const int lane = tid & 63, wid = tid >> 6;
  const int c = min(cnt[row], CAP);
  __shared__ unsigned su[CAP];
  __shared__ float sv[CAP];
  __shared__ int redI[4];
  __shared__ int woff[4];
  __shared__ int basev;
  __shared__ float tv[TOPK];
  __shared__ int ti[TOPK];
  const float* cvr = cand_v + (size_t)row * CAP;
  const int* cir = cand_i + (size_t)row * CAP;
  for (int s = tid; s < c; s += 256) {
    const float v = cvr[s];
    sv[s] = v;
    su[s] = __float_as_uint(v);
  }
  __syncthreads();
  unsigned T = 0u;
  for (int b = 30; b >= 0; --b) {
    const unsigned Tt = T | (1u << b);
    int cg = 0;
    for (int s = tid; s < c; s += 256) cg += (su[s] >= Tt) ? 1 : 0;
#pragma unroll
    for (int o = 32; o > 0; o >>= 1) cg += __shfl_down(cg, o, 64);
    if (lane == 0) redI[wid] = cg;
    __syncthreads();
    const int tot = redI[0] + redI[1] + redI[2] + redI[3];
    if (tot >= TOPK) T = Tt;
    __syncthreads();
  }
  if (tid == 0) basev = 0;
  __syncthreads();
  for (int s0 = 0; s0 < c; s0 += 256) {
    const int s = s0 + tid;
    const bool take = (s < c) && (su[s] > T);
    const unsigned long long m = __ballot(take);
    const int wsum = __popcll(m);
    const int wpre = __popcll(m & ((1ull << lane) - 1ull));
    if (lane == 0) woff[wid] = wsum;
    __syncthreads();
    int pre = 0;
    for (int w = 0; w < wid; ++w) pre += woff[w];
    const int tot = woff[0] + woff[1] + woff[2] + woff[3];
    if (take) {
      const int p = basev + pre + wpre;
      tv[p] = sv[s];
      ti[p] = cir[s];
    }
    __syncthreads();
    if (tid == 0) basev += tot;
    __syncthreads();
  }
  for (int s0 = 0; s0 < c; s0 += 256) {
    const int s = s0 + tid;
    const bool take = (s < c) && (su[s] == T);
    const unsigned long long m = __ballot(take);
    const int wsum = __popcll(m);
    const int wpre = __popcll(m & ((1ull << lane) - 1ull));
    if (lane == 0) woff[wid] = wsum;
    __syncthreads();
    int pre = 0;
    for (int w = 0; w < wid; ++w) pre += woff[w];
    const int tot = woff[0] + woff[1] + woff[2] + woff[3];
    if (take) {
      const int p = basev + pre + wpre;
      if (p < TOPK) {
        tv[p] = sv[s];
        ti[p] = cir[s];
      }
    }
    __syncthreads();
    if (tid == 0) basev += tot;
    __syncthreads();
  }
  for (int ksz = 2; ksz <= TOPK; ksz <<= 1) {
    for (int js = ksz >> 1; js > 0; js >>= 1) {
      if (tid < TOPK) {
        const int partner = tid ^ js;
        if (partner > tid) {
          const bool up = ((tid & ksz) == 0);
          const int a = ti[tid], b2 = ti[partner];
          if ((a > b2) == up) {
            ti[tid] = b2;
            ti[partner] = a;
            const float fa = tv[tid];
            tv[tid] = tv[partner];
            tv[partner] = fa;
          }
        }
      }
      __syncthreads();
    }
  }
  if (tid < TOPK) {
    top_v[(size_t)row * TOPK + tid] = tv[tid];
    top_i[(size_t)row * TOPK + tid] = ti[tid];
  }
}

__global__ __launch_bounds__(192) void k_decode(const float* __restrict__ top_v,
                                                const int* __restrict__ top_i,
                                                const float* __restrict__ W_dec,
                                                const float* __restrict__ b_dec,
                                                float* __restrict__ out) {
  const int row = blockIdx.x;
  const int tid = threadIdx.x;
  __shared__ float v[TOPK];
  __shared__ int ix[TOPK];
  if (tid < TOPK) {
    v[tid] = top_v[(size_t)row * TOPK + tid];
    ix[tid] = top_i[(size_t)row * TOPK + tid];
  }
  __syncthreads();
  const int d = tid * 4;
  float4 acc = *(const float4*)(b_dec + d);
#pragma unroll 8
  for (int k = 0; k < TOPK; ++k) {
    const float4 w = *(const float4*)(W_dec + (size_t)ix[k] * DIN + d);
    const float vk = v[k];
    acc.x = fmaf(vk, w.x, acc.x);
    acc.y = fmaf(vk, w.y, acc.y);
    acc.z = fmaf(vk, w.z, acc.z);
    acc.w = fmaf(vk, w.w, acc.w);
  }
  *(float4*)(out + (size_t)row * DIN + d) = acc;
}

extern "C" void kernel_launch(void* const* d_in, const int* in_sizes, int n_in,
                              void* d_out, int out_size, void* d_ws, size_t ws_size,
                              hipStream_t stream) {
  const float* x = (const float*)d_in[0];
  const float* W_enc = (const float*)d_in[1];
  const float* b_enc = (const float*)d_in[2];
  const float* W_dec = (const float*)d_in[3];
  const float* b_dec = (const float*)d_in[4];
  float* out = (float*)d_out;

  char* p = (char*)d_ws;
  auto alloc = [&](size_t bytes) {
    char* r = p;
    p += (bytes + 255) & ~(size_t)255;
    return r;
  };
  float* tau = (float*)alloc((size_t)NTOK * 4);
  int* cnt = (int*)alloc((size_t)NTOK * 4);
  int* band_cnt = (int*)alloc(256);
  int* band_list = (int*)alloc((size_t)BANDCAP * 4);
  float* cand_v = (float*)alloc((size_t)NTOK * CAP * 4);
  int* cand_i = (int*)alloc((size_t)NTOK * CAP * 4);
  float* top_v = (float*)alloc((size_t)NTOK * TOPK * 4);
  int* top_i = (int*)alloc((size_t)NTOK * TOPK * 4);
  float* xm = (float*)alloc((size_t)NTOK * DIN * 4);
  ushort* Ah = (ushort*)alloc((size_t)NTOK * DIN * 2);
  ushort* Bth = (ushort*)alloc((size_t)DSAE * DIN * 2);
  float* Wt = (float*)alloc((size_t)DSAE * DIN * 4);
  const bool fastT = ((size_t)(p - (char*)d_ws) <= ws_size);

  const int nconv = (DIN / 32) * (DSAE / 128);  // 6144
  hipLaunchKernelGGL(k_pre, dim3(nconv + NTOK), dim3(256), 0, stream,
                     x, b_dec, xm, Ah, tau, cnt, band_cnt, W_enc, Wt, Bth, (int)fastT);
  hipLaunchKernelGGL(k_gemm_mfma, dim3((NTOK / GBM) * (DSAE / GBN)), dim3(256), 0, stream,
                     Ah, Bth, b_enc, tau, cnt, cand_v, cand_i);
  if (fastT) {
    hipLaunchKernelGGL(k_selref, dim3(NTOK), dim3(256), 0, stream,
                       cnt, cand_v, cand_i, xm, Wt, b_enc, W_dec, b_dec, out);
  } else {
    hipLaunchKernelGGL(k_band, dim3(NTOK), dim3(256), 0, stream, cnt, cand_v, band_cnt, band_list);
    hipLaunchKernelGGL(k_refine, dim3(BANDCAP / 256), dim3(256), 0, stream,
                       band_cnt, band_list, xm, W_enc, b_enc, cand_v, cand_i);
    hipLaunchKernelGGL(k_select, dim3(NTOK), dim3(256), 0, stream, cnt, cand_v, cand_i, top_v, top_i);
    hipLaunchKernelGGL(k_decode, dim3(NTOK), dim3(192), 0, stream, top_v, top_i, W_dec, b_dec, out);
  }
}

// Round 9
// 430.218 us; speedup vs baseline: 1.0822x; 1.0822x over previous
//
#include <hip/hip_runtime.h>
#include <stdint.h>
#include <math.h>

#define NTOK 4096
#define DIN  768
#define DSAE 32768
#define TOPK 64
#define CAP  512
#define CAPLOG 9
#define ZCOEF 0.05f
#define BAND 0.008f
#define BANDCAP 65536
#define BMAX 64

#define GBM 128
#define GBN 256
#define GBK 32
#define NT  (DIN / GBK)      // 24 k-steps
#define SLOT 24576           // 8KB A + 16KB B per ring slot
#define SEGC 24              // per-row per-block candidate cap

typedef float f32x4 __attribute__((ext_vector_type(4)));
typedef short short8 __attribute__((ext_vector_type(8)));

__device__ __forceinline__ ushort f2bf(float f) {
  uint32_t u = __float_as_uint(f);
  return (ushort)((u + 0x7fffu + ((u >> 16) & 1u)) >> 16);
}
__device__ __forceinline__ int swz(int o) { return o ^ (((o >> 7) & 3) << 4); }

// ---------------- K_pre: fused convT (blocks 0..6143) + prepA (blocks 6144..10239) ----------------
__global__ __launch_bounds__(256) void k_pre(const float* __restrict__ x,
                                             const float* __restrict__ b_dec,
                                             ushort* __restrict__ Ah,
                                             float* __restrict__ tau,
                                             int* __restrict__ cnt,
                                             int* __restrict__ band_cnt,
                                             const float* __restrict__ W,
                                             float* __restrict__ Wt,
                                             ushort* __restrict__ Bth,
                                             int doWt) {
  __shared__ float Lf[128][33];
  __shared__ float red[4];
  const int bid = blockIdx.x;
  const int t = threadIdx.x;

  if (bid < (DIN / 32) * (DSAE / 128)) {
    // ---- convT part: Wt[n][k] = W_enc[k][n] fp32 (gated) + Bth bf16 ----
    const int bk = bid % (DIN / 32);
    const int bn = bid / (DIN / 32);
#pragma unroll
    for (int q = 0; q < 4; ++q) {
      const int idx = q * 256 + t;
      const int k = idx >> 5;
      const int n4 = (idx & 31) * 4;
      const float4 w = *(const float4*)(W + (size_t)(bk * 32 + k) * DSAE + (size_t)bn * 128 + n4);
      Lf[n4 + 0][k] = w.x;
      Lf[n4 + 1][k] = w.y;
      Lf[n4 + 2][k] = w.z;
      Lf[n4 + 3][k] = w.w;
    }
    __syncthreads();
#pragma unroll
    for (int q = 0; q < 4; ++q) {
      const int idx = q * 256 + t;
      const int n = idx >> 3;
      const int k4 = (idx & 7) * 4;
      float4 v;
      v.x = Lf[n][k4 + 0]; v.y = Lf[n][k4 + 1]; v.z = Lf[n][k4 + 2]; v.w = Lf[n][k4 + 3];
      const size_t ob = (size_t)(bn * 128 + n) * DIN + bk * 32 + k4;
      if (doWt) *(float4*)(Wt + ob) = v;
      ushort4 hh;
      hh.x = f2bf(v.x); hh.y = f2bf(v.y); hh.z = f2bf(v.z); hh.w = f2bf(v.w);
      *(ushort4*)(Bth + ob) = hh;
    }
  } else {
    // ---- prepA part: Ah = bf16(x - b_dec), tau, zero counters ----
    const int row = bid - (DIN / 32) * (DSAE / 128);
    float ss = 0.f;
    if (t < 192) {
      const float4 xv = *(const float4*)(x + (size_t)row * DIN + t * 4);
      const float4 bd = *(const float4*)(b_dec + t * 4);
      const float a0 = xv.x - bd.x, a1 = xv.y - bd.y, a2 = xv.z - bd.z, a3 = xv.w - bd.w;
      ushort4 h;
      h.x = f2bf(a0); h.y = f2bf(a1); h.z = f2bf(a2); h.w = f2bf(a3);
      *(ushort4*)(Ah + (size_t)row * DIN + t * 4) = h;
      ss = a0 * a0 + a1 * a1 + a2 * a2 + a3 * a3;
    }
#pragma unroll
    for (int o = 32; o > 0; o >>= 1) ss += __shfl_down(ss, o, 64);
    const int lane = t & 63, wid = t >> 6;
    if (lane == 0) red[wid] = ss;
    __syncthreads();
    if (t == 0) {
      tau[row] = ZCOEF * sqrtf(red[0] + red[1] + red[2] + red[3]);
      cnt[row] = 0;
      if (row == 0) band_cnt[0] = 0;
    }
  }
}

// ---------------- K1: bf16 MFMA GEMM — R7-exact (512 thr, 8 waves 64x64, 3-slot, vmcnt(3)) ----------------
#define GLD(srcp, dstp) __builtin_amdgcn_global_load_lds( \
    (const __attribute__((address_space(1))) void*)(srcp), \
    (__attribute__((address_space(3))) void*)(dstp), 16, 0, 0)

__global__ __launch_bounds__(512, 4) void k_gemm_mfma(const ushort* __restrict__ Ah,
                                                      const ushort* __restrict__ Bth,
                                                      const float* __restrict__ b_enc,
                                                      const float* __restrict__ tau,
                                                      int* __restrict__ cnt,
                                                      float* __restrict__ cand_v,
                                                      int* __restrict__ cand_i) {
  __shared__ __align__(16) char smem[3 * SLOT];  // 72 KB ring: per slot 8KB A + 16KB B

  const int bid = blockIdx.x;
  const int xcd = bid & 7;
  const int i = bid >> 3;       // 0..511
  const int j = i & 15;
  const int st = i >> 4;        // 0..31
  const int bmg = st >> 3;      // 0..3
  const int bng = st & 7;       // 0..7
  const int bm = bmg * 8 + (j >> 1);             // 0..31
  const int bn = xcd * 16 + bng * 2 + (j & 1);   // 0..127

  const int t = threadIdx.x;
  const int lane = t & 63, wid = t >> 6;
  const int wr = wid >> 2, wc = wid & 3;     // 2 x 4 waves, each 64x64 out
  const int fr = lane & 15, fg = lane >> 4;

  f32x4 acc[4][4];
#pragma unroll
  for (int m = 0; m < 4; ++m)
#pragma unroll
    for (int n = 0; n < 4; ++n) acc[m][n] = (f32x4)0.f;

  const int oA = t * 16;
  const int LA = swz(oA);
  const int rA = LA >> 6, eA = (LA & 63) >> 1;
  const int oB0 = t * 16, oB1 = (t + 512) * 16;
  const int LB0 = swz(oB0), LB1 = swz(oB1);
  const int rB0 = LB0 >> 6, eB0 = (LB0 & 63) >> 1;
  const int rB1 = LB1 >> 6, eB1 = (LB1 & 63) >> 1;

  const size_t aRow = (size_t)bm * GBM;
  const size_t bRow = (size_t)bn * GBN;

  auto stage = [&](int slot, int kt) {
    const int k0 = kt * GBK;
    char* sA = smem + slot * SLOT;
    char* sB = sA + 8192;
    GLD(Ah + (aRow + rA) * DIN + k0 + eA, sA + oA);
    GLD(Bth + (bRow + rB0) * DIN + k0 + eB0, sB + oB0);
    GLD(Bth + (bRow + rB1) * DIN + k0 + eB1, sB + oB1);
  };

  stage(0, 0);
  stage(1, 1);

  for (int kt = 0; kt < NT; ++kt) {
    // wait only for tile kt's 3 loads; tile kt+1's stay in flight across the barrier
    if (kt < NT - 1) {
      asm volatile("s_waitcnt vmcnt(3)" ::: "memory");
    } else {
      asm volatile("s_waitcnt vmcnt(0)" ::: "memory");
    }
    __builtin_amdgcn_s_barrier();
    if (kt + 2 < NT) stage((kt + 2) % 3, kt + 2);

    const char* sA = smem + (kt % 3) * SLOT;
    const char* sB = sA + 8192;
    short8 ah[4], bh[4];
#pragma unroll
    for (int m = 0; m < 4; ++m) {
      const int L = ((wr * 64 + m * 16 + fr) << 6) | (fg << 4);
      ah[m] = *(const short8*)(sA + swz(L));
    }
#pragma unroll
    for (int n = 0; n < 4; ++n) {
      const int L = ((wc * 64 + n * 16 + fr) << 6) | (fg << 4);
      bh[n] = *(const short8*)(sB + swz(L));
    }
#pragma unroll
    for (int m = 0; m < 4; ++m)
#pragma unroll
      for (int n = 0; n < 4; ++n)
        acc[m][n] = __builtin_amdgcn_mfma_f32_16x16x32_bf16(ah[m], bh[n], acc[m][n], 0, 0, 0);
  }

  // -------- epilogue: LDS-aggregated candidate append --------
  __syncthreads();
  uint2* seg = (uint2*)smem;                   // [128][SEGC] (24 KB)
  int* lcnt = (int*)(smem + 128 * SEGC * 8);   // 128 ints
  if (t < 128) lcnt[t] = 0;
  __syncthreads();

  const int rbase = bm * GBM;
#pragma unroll
  for (int m = 0; m < 4; ++m) {
#pragma unroll
    for (int jj = 0; jj < 4; ++jj) {
      const int row_l = wr * 64 + m * 16 + fg * 4 + jj;
      const float trow = tau[rbase + row_l];
#pragma unroll
      for (int n = 0; n < 4; ++n) {
        const int col = bn * GBN + wc * 64 + n * 16 + fr;
        const float v = acc[m][n][jj] + b_enc[col];
        if (v > trow) {
          const int sl = atomicAdd(&lcnt[row_l], 1);
          if (sl < SEGC) seg[row_l * SEGC + sl] = make_uint2(__float_as_uint(v), (unsigned)col);
        }
      }
    }
  }
  __syncthreads();
  if (t < 128) {
    const int c = min(lcnt[t], SEGC);
    if (c > 0) {
      const int base = atomicAdd(&cnt[rbase + t], c);
      for (int s2 = 0; s2 < c; ++s2) {
        const int pos = base + s2;
        if (pos < CAP) {
          const uint2 e = seg[t * SEGC + s2];
          cand_v[(size_t)(rbase + t) * CAP + pos] = __uint_as_float(e.x);
          cand_i[(size_t)(rbase + t) * CAP + pos] = (int)e.y;
        }
      }
    }
  }
}

// ---------------- K_selref: fused band + refine + select + decode (fast path) ----------------
__global__ __launch_bounds__(256) void k_selref(const int* __restrict__ cnt,
                                                const float* __restrict__ cand_v,
                                                const int* __restrict__ cand_i,
                                                const float* __restrict__ x,
                                                const float* __restrict__ Wt,
                                                const float* __restrict__ b_enc,
                                                const float* __restrict__ W_dec,
                                                const float* __restrict__ b_dec,
                                                float* __restrict__ out) {
  const int row = blockIdx.x;
  const int tid = threadIdx.x;
  const int lane = tid & 63, wid = tid >> 6;
  const int c = min(cnt[row], CAP);

  __shared__ unsigned su[CAP];
  __shared__ float sv[CAP];
  __shared__ float xr[DIN];
  __shared__ int redI[4];
  __shared__ int woff[4];
  __shared__ int basev;
  __shared__ int nband;
  __shared__ int bandl[BMAX];
  __shared__ float tv[TOPK];
  __shared__ int ti[TOPK];

  const float* cvr = cand_v + (size_t)row * CAP;
  const int* cir = cand_i + (size_t)row * CAP;
  for (int s = tid; s < c; s += 256) {
    const float v = cvr[s];
    sv[s] = v;
    su[s] = __float_as_uint(v);
  }
  // xr = x - b_dec (same fp32 subtract as k_pre / all prior rounds)
  xr[tid] = x[(size_t)row * DIN + tid] - b_dec[tid];
  xr[tid + 256] = x[(size_t)row * DIN + tid + 256] - b_dec[tid + 256];
  xr[tid + 512] = x[(size_t)row * DIN + tid + 512] - b_dec[tid + 512];
  if (tid == 0) nband = 0;
  __syncthreads();

  // radix pass 1: approx 64th-largest (on GEMM values)
  unsigned T = 0u;
  for (int b = 30; b >= 0; --b) {
    const unsigned Tt = T | (1u << b);
    int cg = 0;
    for (int s = tid; s < c; s += 256) cg += (su[s] >= Tt) ? 1 : 0;
#pragma unroll
    for (int o = 32; o > 0; o >>= 1) cg += __shfl_down(cg, o, 64);
    if (lane == 0) redI[wid] = cg;
    __syncthreads();
    const int tot = redI[0] + redI[1] + redI[2] + redI[3];
    if (tot >= TOPK) T = Tt;
    __syncthreads();
  }
  const float Ta = __uint_as_float(T);

  // collect band entries
  for (int s = tid; s < c; s += 256) {
    const float v = sv[s];
    if (v >= Ta - BAND && v <= Ta + BAND) {
      const int p = atomicAdd(&nband, 1);
      if (p < BMAX) bandl[p] = s;
    }
  }
  __syncthreads();
  const int nb = min(nband, BMAX);

  // refine: wave per entry, same arithmetic as R4-R8 k_refineT
  for (int e = wid; e < nb; e += 4) {
    const int s = bandl[e];
    const int col = cir[s];
    const float* wrow = Wt + (size_t)col * DIN;
    float acc = 0.f;
#pragma unroll
    for (int jj = 0; jj < 3; ++jj) {
      const float4 a = *(const float4*)&xr[lane * 4 + jj * 256];
      const float4 w = *(const float4*)(wrow + lane * 4 + jj * 256);
      acc = fmaf(a.x, w.x, acc);
      acc = fmaf(a.y, w.y, acc);
      acc = fmaf(a.z, w.z, acc);
      acc = fmaf(a.w, w.w, acc);
    }
#pragma unroll
    for (int o = 32; o > 0; o >>= 1) acc += __shfl_down(acc, o, 64);
    if (lane == 0) {
      const float nv = acc + b_enc[col];
      sv[s] = nv;
      su[s] = __float_as_uint(nv);
    }
  }
  __syncthreads();

  // radix pass 2: exact 64th-largest on corrected values
  T = 0u;
  for (int b = 30; b >= 0; --b) {
    const unsigned Tt = T | (1u << b);
    int cg = 0;
    for (int s = tid; s < c; s += 256) cg += (su[s] >= Tt) ? 1 : 0;
#pragma unroll
    for (int o = 32; o > 0; o >>= 1) cg += __shfl_down(cg, o, 64);
    if (lane == 0) redI[wid] = cg;
    __syncthreads();
    const int tot = redI[0] + redI[1] + redI[2] + redI[3];
    if (tot >= TOPK) T = Tt;
    __syncthreads();
  }

  if (tid == 0) basev = 0;
  __syncthreads();
  for (int s0 = 0; s0 < c; s0 += 256) {
    const int s = s0 + tid;
    const bool take = (s < c) && (su[s] > T);
    const unsigned long long m = __ballot(take);
    const int wsum = __popcll(m);
    const int wpre = __popcll(m & ((1ull << lane) - 1ull));
    if (lane == 0) woff[wid] = wsum;
    __syncthreads();
    int pre = 0;
    for (int w = 0; w < wid; ++w) pre += woff[w];
    const int tot = woff[0] + woff[1] + woff[2] + woff[3];
    if (take) {
      const int p = basev + pre + wpre;
      tv[p] = sv[s];
      ti[p] = cir[s];
    }
    __syncthreads();
    if (tid == 0) basev += tot;
    __syncthreads();
  }
  for (int s0 = 0; s0 < c; s0 += 256) {
    const int s = s0 + tid;
    const bool take = (s < c) && (su[s] == T);
    const unsigned long long m = __ballot(take);
    const int wsum = __popcll(m);
    const int wpre = __popcll(m & ((1ull << lane) - 1ull));
    if (lane == 0) woff[wid] = wsum;
    __syncthreads();
    int pre = 0;
    for (int w = 0; w < wid; ++w) pre += woff[w];
    const int tot = woff[0] + woff[1] + woff[2] + woff[3];
    if (take) {
      const int p = basev + pre + wpre;
      if (p < TOPK) {
        tv[p] = sv[s];
        ti[p] = cir[s];
      }
    }
    __syncthreads();
    if (tid == 0) basev += tot;
    __syncthreads();
  }

  for (int ksz = 2; ksz <= TOPK; ksz <<= 1) {
    for (int js = ksz >> 1; js > 0; js >>= 1) {
      if (tid < TOPK) {
        const int partner = tid ^ js;
        if (partner > tid) {
          const bool up = ((tid & ksz) == 0);
          const int a = ti[tid], b2 = ti[partner];
          if ((a > b2) == up) {
            ti[tid] = b2;
            ti[partner] = a;
            const float fa = tv[tid];
            tv[tid] = tv[partner];
            tv[partner] = fa;
          }
        }
      }
      __syncthreads();
    }
  }

  if (tid < 192) {
    const int d = tid * 4;
    float4 acc = *(const float4*)(b_dec + d);
#pragma unroll 8
    for (int k = 0; k < TOPK; ++k) {
      const float4 w = *(const float4*)(W_dec + (size_t)ti[k] * DIN + d);
      const float vk = tv[k];
      acc.x = fmaf(vk, w.x, acc.x);
      acc.y = fmaf(vk, w.y, acc.y);
      acc.z = fmaf(vk, w.z, acc.z);
      acc.w = fmaf(vk, w.w, acc.w);
    }
    *(float4*)(out + (size_t)row * DIN + d) = acc;
  }
}

// ================= fallback chain (ws too small for Wt) =================
__global__ __launch_bounds__(256) void k_band(const int* __restrict__ cnt,
                                              const float* __restrict__ cand_v,
                                              int* __restrict__ band_cnt,
                                              int* __restrict__ band_list) {
  const int row = blockIdx.x;
  const int tid = threadIdx.x;
  const int lane = tid & 63, wid = tid >> 6;
  const int c = min(cnt[row], CAP);
  __shared__ unsigned su[CAP];
  __shared__ int redI[4];
  const float* cvr = cand_v + (size_t)row * CAP;
  for (int s = tid; s < c; s += 256) su[s] = __float_as_uint(cvr[s]);
  __syncthreads();
  unsigned T = 0u;
  for (int b = 30; b >= 0; --b) {
    const unsigned Tt = T | (1u << b);
    int cg = 0;
    for (int s = tid; s < c; s += 256) cg += (su[s] >= Tt) ? 1 : 0;
#pragma unroll
    for (int o = 32; o > 0; o >>= 1) cg += __shfl_down(cg, o, 64);
    if (lane == 0) redI[wid] = cg;
    __syncthreads();
    const int tot = redI[0] + redI[1] + redI[2] + redI[3];
    if (tot >= TOPK) T = Tt;
    __syncthreads();
  }
  const float Tf = __uint_as_float(T);
  for (int s = tid; s < c; s += 256) {
    const float v = __uint_as_float(su[s]);
    if (v >= Tf - BAND && v <= Tf + BAND) {
      const int p = atomicAdd(band_cnt, 1);
      if (p < BANDCAP) band_list[p] = (row << CAPLOG) + s;
    }
  }
}

__global__ __launch_bounds__(256) void k_refine(const int* __restrict__ band_cnt,
                                                const int* __restrict__ band_list,
                                                const float* __restrict__ x,
                                                const float* __restrict__ b_dec,
                                                const float* __restrict__ W_enc,
                                                const float* __restrict__ b_enc,
                                                float* __restrict__ cand_v,
                                                const int* __restrict__ cand_i) {
  const int i = blockIdx.x * 256 + threadIdx.x;
  const int nb = min(band_cnt[0], BANDCAP);
  if (i >= nb) return;
  const int e = band_list[i];
  const int row = e >> CAPLOG;
  const int s = e & (CAP - 1);
  const int col = cand_i[(size_t)row * CAP + s];
  const float* xr = x + (size_t)row * DIN;
  float acc = 0.f;
  for (int k = 0; k < DIN; ++k)
    acc = fmaf(xr[k] - b_dec[k], W_enc[(size_t)k * DSAE + col], acc);
  cand_v[(size_t)row * CAP + s] = acc + b_enc[col];
}

__global__ __launch_bounds__(256) void k_select(const int* __restrict__ cnt,
                                                const float* __restrict__ cand_v,
                                                const int* __restrict__ cand_i,
                                                float* __restrict__ top_v,
                                                int* __restrict__ top_i) {
  const int row = blockIdx.x;
  const int tid = threadIdx.x;
  const int lane = tid & 63, wid = tid >> 6;
  const int c = min(cnt[row], CAP);
  __shared__ unsigned su[CAP];
  __shared__ float sv[CAP];
  __shared__ int redI[4];
  __shared__ int woff[4];
  __shared__ int basev;
  __shared__ float tv[TOPK];
  __shared__ int ti[TOPK];
  const float* cvr = cand_v + (size_t)row * CAP;
  const int* cir = cand_i + (size_t)row * CAP;
  for (int s = tid; s < c; s += 256) {
    const float v = cvr[s];
    sv[s] = v;
    su[s] = __float_as_uint(v);
  }
  __syncthreads();
  unsigned T = 0u;
  for (int b = 30; b >= 0; --b) {
    const unsigned Tt = T | (1u << b);
    int cg = 0;
    for (int s = tid; s < c; s += 256) cg += (su[s] >= Tt) ? 1 : 0;
#pragma unroll
    for (int o = 32; o > 0; o >>= 1) cg += __shfl_down(cg, o, 64);
    if (lane == 0) redI[wid] = cg;
    __syncthreads();
    const int tot = redI[0] + redI[1] + redI[2] + redI[3];
    if (tot >= TOPK) T = Tt;
    __syncthreads();
  }
  if (tid == 0) basev = 0;
  __syncthreads();
  for (int s0 = 0; s0 < c; s0 += 256) {
    const int s = s0 + tid;
    const bool take = (s < c) && (su[s] > T);
    const unsigned long long m = __ballot(take);
    const int wsum = __popcll(m);
    const int wpre = __popcll(m & ((1ull << lane) - 1ull));
    if (lane == 0) woff[wid] = wsum;
    __syncthreads();
    int pre = 0;
    for (int w = 0; w < wid; ++w) pre += woff[w];
    const int tot = woff[0] + woff[1] + woff[2] + woff[3];
    if (take) {
      const int p = basev + pre + wpre;
      tv[p] = sv[s];
      ti[p] = cir[s];
    }
    __syncthreads();
    if (tid == 0) basev += tot;
    __syncthreads();
  }
  for (int s0 = 0; s0 < c; s0 += 256) {
    const int s = s0 + tid;
    const bool take = (s < c) && (su[s] == T);
    const unsigned long long m = __ballot(take);
    const int wsum = __popcll(m);
    const int wpre = __popcll(m & ((1ull << lane) - 1ull));
    if (lane == 0) woff[wid] = wsum;
    __syncthreads();
    int pre = 0;
    for (int w = 0; w < wid; ++w) pre += woff[w];
    const int tot = woff[0] + woff[1] + woff[2] + woff[3];
    if (take) {
      const int p = basev + pre + wpre;
      if (p < TOPK) {
        tv[p] = sv[s];
        ti[p] = cir[s];
      }
    }
    __syncthreads();
    if (tid == 0) basev += tot;
    __syncthreads();
  }
  for (int ksz = 2; ksz <= TOPK; ksz <<= 1) {
    for (int js = ksz >> 1; js > 0; js >>= 1) {
      if (tid < TOPK) {
        const int partner = tid ^ js;
        if (partner > tid) {
          const bool up = ((tid & ksz) == 0);
          const int a = ti[tid], b2 = ti[partner];
          if ((a > b2) == up) {
            ti[tid] = b2;
            ti[partner] = a;
            const float fa = tv[tid];
            tv[tid] = tv[partner];
            tv[partner] = fa;
          }
        }
      }
      __syncthreads();
    }
  }
  if (tid < TOPK) {
    top_v[(size_t)row * TOPK + tid] = tv[tid];
    top_i[(size_t)row * TOPK + tid] = ti[tid];
  }
}

__global__ __launch_bounds__(192) void k_decode(const float* __restrict__ top_v,
                                                const int* __restrict__ top_i,
                                                const float* __restrict__ W_dec,
                                                const float* __restrict__ b_dec,
                                                float* __restrict__ out) {
  const int row = blockIdx.x;
  const int tid = threadIdx.x;
  __shared__ float v[TOPK];
  __shared__ int ix[TOPK];
  if (tid < TOPK) {
    v[tid] = top_v[(size_t)row * TOPK + tid];
    ix[tid] = top_i[(size_t)row * TOPK + tid];
  }
  __syncthreads();
  const int d = tid * 4;
  float4 acc = *(const float4*)(b_dec + d);
#pragma unroll 8
  for (int k = 0; k < TOPK; ++k) {
    const float4 w = *(const float4*)(W_dec + (size_t)ix[k] * DIN + d);
    const float vk = v[k];
    acc.x = fmaf(vk, w.x, acc.x);
    acc.y = fmaf(vk, w.y, acc.y);
    acc.z = fmaf(vk, w.z, acc.z);
    acc.w = fmaf(vk, w.w, acc.w);
  }
  *(float4*)(out + (size_t)row * DIN + d) = acc;
}

extern "C" void kernel_launch(void* const* d_in, const int* in_sizes, int n_in,
                              void* d_out, int out_size, void* d_ws, size_t ws_size,
                              hipStream_t stream) {
  const float* x = (const float*)d_in[0];
  const float* W_enc = (const float*)d_in[1];
  const float* b_enc = (const float*)d_in[2];
  const float* W_dec = (const float*)d_in[3];
  const float* b_dec = (const float*)d_in[4];
  float* out = (float*)d_out;

  char* p = (char*)d_ws;
  auto alloc = [&](size_t bytes) {
    char* r = p;
    p += (bytes + 255) & ~(size_t)255;
    return r;
  };
  float* tau = (float*)alloc((size_t)NTOK * 4);
  int* cnt = (int*)alloc((size_t)NTOK * 4);
  int* band_cnt = (int*)alloc(256);
  int* band_list = (int*)alloc((size_t)BANDCAP * 4);
  float* cand_v = (float*)alloc((size_t)NTOK * CAP * 4);
  int* cand_i = (int*)alloc((size_t)NTOK * CAP * 4);
  float* top_v = (float*)alloc((size_t)NTOK * TOPK * 4);
  int* top_i = (int*)alloc((size_t)NTOK * TOPK * 4);
  ushort* Ah = (ushort*)alloc((size_t)NTOK * DIN * 2);
  ushort* Bth = (ushort*)alloc((size_t)DSAE * DIN * 2);
  float* Wt = (float*)alloc((size_t)DSAE * DIN * 4);
  const bool fastT = ((size_t)(p - (char*)d_ws) <= ws_size);

  const int nconv = (DIN / 32) * (DSAE / 128);  // 6144
  hipLaunchKernelGGL(k_pre, dim3(nconv + NTOK), dim3(256), 0, stream,
                     x, b_dec, Ah, tau, cnt, band_cnt, W_enc, Wt, Bth, (int)fastT);
  hipLaunchKernelGGL(k_gemm_mfma, dim3((NTOK / GBM) * (DSAE / GBN)), dim3(512), 0, stream,
                     Ah, Bth, b_enc, tau, cnt, cand_v, cand_i);
  if (fastT) {
    hipLaunchKernelGGL(k_selref, dim3(NTOK), dim3(256), 0, stream,
                       cnt, cand_v, cand_i, x, Wt, b_enc, W_dec, b_dec, out);
  } else {
    hipLaunchKernelGGL(k_band, dim3(NTOK), dim3(256), 0, stream, cnt, cand_v, band_cnt, band_list);
    hipLaunchKernelGGL(k_refine, dim3(BANDCAP / 256), dim3(256), 0, stream,
                       band_cnt, band_list, x, b_dec, W_enc, b_enc, cand_v, cand_i);
    hipLaunchKernelGGL(k_select, dim3(NTOK), dim3(256), 0, stream, cnt, cand_v, cand_i, top_v, top_i);
    hipLaunchKernelGGL(k_decode, dim3(NTOK), dim3(192), 0, stream, top_v, top_i, W_dec, b_dec, out);
  }
}

// Round 10
// 392.028 us; speedup vs baseline: 1.1876x; 1.0974x over previous
//
#include <hip/hip_runtime.h>
#include <stdint.h>
#include <math.h>

#define NTOK 4096
#define DIN  768
#define DSAE 32768
#define TOPK 64
#define CAP  512
#define CAPLOG 9
#define ZCOEF 0.05f
#define BAND 0.008f
#define BANDCAP 65536
#define BMAX 64

#define GBM 128
#define GBN 256
#define GBK 32
#define NT  (DIN / GBK)      // 24 k-steps
#define SLOT 24576           // 8KB A + 16KB B per ring slot
#define SEGC 24              // per-row per-block candidate cap

typedef float f32x4 __attribute__((ext_vector_type(4)));
typedef short short8 __attribute__((ext_vector_type(8)));

__device__ __forceinline__ ushort f2bf(float f) {
  uint32_t u = __float_as_uint(f);
  return (ushort)((u + 0x7fffu + ((u >> 16) & 1u)) >> 16);
}
__device__ __forceinline__ int swz(int o) { return o ^ (((o >> 7) & 3) << 4); }

// ---------------- K_pre: fused convT (blocks 0..6143) + prepA (blocks 6144..10239) ----------------
__global__ __launch_bounds__(256) void k_pre(const float* __restrict__ x,
                                             const float* __restrict__ b_dec,
                                             ushort* __restrict__ Ah,
                                             float* __restrict__ tau,
                                             int* __restrict__ cnt,
                                             int* __restrict__ band_cnt,
                                             const float* __restrict__ W,
                                             float* __restrict__ Wt,
                                             ushort* __restrict__ Bth,
                                             int doWt) {
  __shared__ float Lf[128][33];
  __shared__ float red[4];
  const int bid = blockIdx.x;
  const int t = threadIdx.x;

  if (bid < (DIN / 32) * (DSAE / 128)) {
    const int bk = bid % (DIN / 32);
    const int bn = bid / (DIN / 32);
#pragma unroll
    for (int q = 0; q < 4; ++q) {
      const int idx = q * 256 + t;
      const int k = idx >> 5;
      const int n4 = (idx & 31) * 4;
      const float4 w = *(const float4*)(W + (size_t)(bk * 32 + k) * DSAE + (size_t)bn * 128 + n4);
      Lf[n4 + 0][k] = w.x;
      Lf[n4 + 1][k] = w.y;
      Lf[n4 + 2][k] = w.z;
      Lf[n4 + 3][k] = w.w;
    }
    __syncthreads();
#pragma unroll
    for (int q = 0; q < 4; ++q) {
      const int idx = q * 256 + t;
      const int n = idx >> 3;
      const int k4 = (idx & 7) * 4;
      float4 v;
      v.x = Lf[n][k4 + 0]; v.y = Lf[n][k4 + 1]; v.z = Lf[n][k4 + 2]; v.w = Lf[n][k4 + 3];
      const size_t ob = (size_t)(bn * 128 + n) * DIN + bk * 32 + k4;
      if (doWt) *(float4*)(Wt + ob) = v;
      ushort4 hh;
      hh.x = f2bf(v.x); hh.y = f2bf(v.y); hh.z = f2bf(v.z); hh.w = f2bf(v.w);
      *(ushort4*)(Bth + ob) = hh;
    }
  } else {
    const int row = bid - (DIN / 32) * (DSAE / 128);
    float ss = 0.f;
    if (t < 192) {
      const float4 xv = *(const float4*)(x + (size_t)row * DIN + t * 4);
      const float4 bd = *(const float4*)(b_dec + t * 4);
      const float a0 = xv.x - bd.x, a1 = xv.y - bd.y, a2 = xv.z - bd.z, a3 = xv.w - bd.w;
      ushort4 h;
      h.x = f2bf(a0); h.y = f2bf(a1); h.z = f2bf(a2); h.w = f2bf(a3);
      *(ushort4*)(Ah + (size_t)row * DIN + t * 4) = h;
      ss = a0 * a0 + a1 * a1 + a2 * a2 + a3 * a3;
    }
#pragma unroll
    for (int o = 32; o > 0; o >>= 1) ss += __shfl_down(ss, o, 64);
    const int lane = t & 63, wid = t >> 6;
    if (lane == 0) red[wid] = ss;
    __syncthreads();
    if (t == 0) {
      tau[row] = ZCOEF * sqrtf(red[0] + red[1] + red[2] + red[3]);
      cnt[row] = 0;
      if (row == 0) band_cnt[0] = 0;
    }
  }
}

// ---------------- K1: bf16 MFMA GEMM — R9-exact (512 thr, 8 waves 64x64, 3-slot, vmcnt(3)) ----------------
#define GLD(srcp, dstp) __builtin_amdgcn_global_load_lds( \
    (const __attribute__((address_space(1))) void*)(srcp), \
    (__attribute__((address_space(3))) void*)(dstp), 16, 0, 0)

__global__ __launch_bounds__(512, 4) void k_gemm_mfma(const ushort* __restrict__ Ah,
                                                      const ushort* __restrict__ Bth,
                                                      const float* __restrict__ b_enc,
                                                      const float* __restrict__ tau,
                                                      int* __restrict__ cnt,
                                                      float* __restrict__ cand_v,
                                                      int* __restrict__ cand_i) {
  __shared__ __align__(16) char smem[3 * SLOT];

  const int bid = blockIdx.x;
  const int xcd = bid & 7;
  const int i = bid >> 3;
  const int j = i & 15;
  const int st = i >> 4;
  const int bmg = st >> 3;
  const int bng = st & 7;
  const int bm = bmg * 8 + (j >> 1);
  const int bn = xcd * 16 + bng * 2 + (j & 1);

  const int t = threadIdx.x;
  const int lane = t & 63, wid = t >> 6;
  const int wr = wid >> 2, wc = wid & 3;
  const int fr = lane & 15, fg = lane >> 4;

  f32x4 acc[4][4];
#pragma unroll
  for (int m = 0; m < 4; ++m)
#pragma unroll
    for (int n = 0; n < 4; ++n) acc[m][n] = (f32x4)0.f;

  const int oA = t * 16;
  const int LA = swz(oA);
  const int rA = LA >> 6, eA = (LA & 63) >> 1;
  const int oB0 = t * 16, oB1 = (t + 512) * 16;
  const int LB0 = swz(oB0), LB1 = swz(oB1);
  const int rB0 = LB0 >> 6, eB0 = (LB0 & 63) >> 1;
  const int rB1 = LB1 >> 6, eB1 = (LB1 & 63) >> 1;

  const size_t aRow = (size_t)bm * GBM;
  const size_t bRow = (size_t)bn * GBN;

  auto stage = [&](int slot, int kt) {
    const int k0 = kt * GBK;
    char* sA = smem + slot * SLOT;
    char* sB = sA + 8192;
    GLD(Ah + (aRow + rA) * DIN + k0 + eA, sA + oA);
    GLD(Bth + (bRow + rB0) * DIN + k0 + eB0, sB + oB0);
    GLD(Bth + (bRow + rB1) * DIN + k0 + eB1, sB + oB1);
  };

  stage(0, 0);
  stage(1, 1);

  for (int kt = 0; kt < NT; ++kt) {
    if (kt < NT - 1) {
      asm volatile("s_waitcnt vmcnt(3)" ::: "memory");
    } else {
      asm volatile("s_waitcnt vmcnt(0)" ::: "memory");
    }
    __builtin_amdgcn_s_barrier();
    if (kt + 2 < NT) stage((kt + 2) % 3, kt + 2);

    const char* sA = smem + (kt % 3) * SLOT;
    const char* sB = sA + 8192;
    short8 ah[4], bh[4];
#pragma unroll
    for (int m = 0; m < 4; ++m) {
      const int L = ((wr * 64 + m * 16 + fr) << 6) | (fg << 4);
      ah[m] = *(const short8*)(sA + swz(L));
    }
#pragma unroll
    for (int n = 0; n < 4; ++n) {
      const int L = ((wc * 64 + n * 16 + fr) << 6) | (fg << 4);
      bh[n] = *(const short8*)(sB + swz(L));
    }
#pragma unroll
    for (int m = 0; m < 4; ++m)
#pragma unroll
      for (int n = 0; n < 4; ++n)
        acc[m][n] = __builtin_amdgcn_mfma_f32_16x16x32_bf16(ah[m], bh[n], acc[m][n], 0, 0, 0);
  }

  __syncthreads();
  uint2* seg = (uint2*)smem;
  int* lcnt = (int*)(smem + 128 * SEGC * 8);
  if (t < 128) lcnt[t] = 0;
  __syncthreads();

  const int rbase = bm * GBM;
#pragma unroll
  for (int m = 0; m < 4; ++m) {
#pragma unroll
    for (int jj = 0; jj < 4; ++jj) {
      const int row_l = wr * 64 + m * 16 + fg * 4 + jj;
      const float trow = tau[rbase + row_l];
#pragma unroll
      for (int n = 0; n < 4; ++n) {
        const int col = bn * GBN + wc * 64 + n * 16 + fr;
        const float v = acc[m][n][jj] + b_enc[col];
        if (v > trow) {
          const int sl = atomicAdd(&lcnt[row_l], 1);
          if (sl < SEGC) seg[row_l * SEGC + sl] = make_uint2(__float_as_uint(v), (unsigned)col);
        }
      }
    }
  }
  __syncthreads();
  if (t < 128) {
    const int c = min(lcnt[t], SEGC);
    if (c > 0) {
      const int base = atomicAdd(&cnt[rbase + t], c);
      for (int s2 = 0; s2 < c; ++s2) {
        const int pos = base + s2;
        if (pos < CAP) {
          const uint2 e = seg[t * SEGC + s2];
          cand_v[(size_t)(rbase + t) * CAP + pos] = __uint_as_float(e.x);
          cand_i[(size_t)(rbase + t) * CAP + pos] = (int)e.y;
        }
      }
    }
  }
}

// ---------------- K_selref: fused band + refine + select + decode (fast path) ----------------
// Selection core: exact k-th-largest via MSB->LSB digit histograms (4 rounds of 8/8/8/7 bits).
// Identical T to the old 31-step bit-search, ~4x fewer scans/barriers.
__global__ __launch_bounds__(256) void k_selref(const int* __restrict__ cnt,
                                                const float* __restrict__ cand_v,
                                                const int* __restrict__ cand_i,
                                                const float* __restrict__ x,
                                                const float* __restrict__ Wt,
                                                const float* __restrict__ b_enc,
                                                const float* __restrict__ W_dec,
                                                const float* __restrict__ b_dec,
                                                float* __restrict__ out) {
  const int row = blockIdx.x;
  const int tid = threadIdx.x;
  const int lane = tid & 63, wid = tid >> 6;
  const int c = min(cnt[row], CAP);

  __shared__ unsigned su[CAP];
  __shared__ float sv[CAP];
  __shared__ float xr[DIN];
  __shared__ int hist[256];
  __shared__ int wtot[4];
  __shared__ int selD[2];
  __shared__ int woff[4];
  __shared__ int basev;
  __shared__ int nband;
  __shared__ int bandl[BMAX];
  __shared__ float tv[TOPK];
  __shared__ int ti[TOPK];

  const float* cvr = cand_v + (size_t)row * CAP;
  const int* cir = cand_i + (size_t)row * CAP;
  for (int s = tid; s < c; s += 256) {
    const float v = cvr[s];
    sv[s] = v;
    su[s] = __float_as_uint(v);
  }
  xr[tid] = x[(size_t)row * DIN + tid] - b_dec[tid];
  xr[tid + 256] = x[(size_t)row * DIN + tid + 256] - b_dec[tid + 256];
  xr[tid + 512] = x[(size_t)row * DIN + tid + 512] - b_dec[tid + 512];
  if (tid == 0) nband = 0;
  __syncthreads();

  // exact/approx 64th-largest via digit histograms
  auto kth_largest = [&](int rounds) -> unsigned {
    const int shv[4] = {23, 15, 7, 0};
    const int wdv[4] = {8, 8, 8, 7};
    unsigned pre = 0;
    int k = TOPK;
    for (int r = 0; r < rounds; ++r) {
      const int shift = shv[r];
      const int NB = 1 << wdv[r];
      hist[tid] = 0;
      __syncthreads();
      const unsigned maskA = ~((1u << (shift + wdv[r])) - 1u);
      for (int s = tid; s < c; s += 256) {
        const unsigned u = su[s];
        if ((u & maskA) == pre) atomicAdd(&hist[(u >> shift) & (NB - 1)], 1);
      }
      __syncthreads();
      const int h = (tid < NB) ? hist[tid] : 0;
      int sfx = h;
#pragma unroll
      for (int o = 1; o < 64; o <<= 1) {
        const int tmp = __shfl_down(sfx, o, 64);
        if (lane + o < 64) sfx += tmp;
      }
      if (lane == 0) wtot[wid] = sfx;
      __syncthreads();
      int S = sfx;
      for (int w = wid + 1; w < (NB >> 6); ++w) S += wtot[w];
      if (tid < NB && S >= k && (S - h) < k) {
        selD[0] = tid;
        selD[1] = k - (S - h);
      }
      __syncthreads();
      pre |= ((unsigned)selD[0]) << shift;
      k = selD[1];
      __syncthreads();
    }
    return pre;
  };

  // pass 1: approx 64th (24 bits; lower bound within 1.6e-5 of exact)
  const float Ta = __uint_as_float(kth_largest(3));

  // collect band entries (upper edge widened by the truncation quantum)
  for (int s = tid; s < c; s += 256) {
    const float v = sv[s];
    if (v >= Ta - BAND && v <= Ta + BAND + 1.0e-4f) {
      const int p = atomicAdd(&nband, 1);
      if (p < BMAX) bandl[p] = s;
    }
  }
  __syncthreads();
  const int nb = min(nband, BMAX);

  // refine: wave per entry, identical arithmetic to R4-R9
  for (int e = wid; e < nb; e += 4) {
    const int s = bandl[e];
    const int col = cir[s];
    const float* wrow = Wt + (size_t)col * DIN;
    float acc = 0.f;
#pragma unroll
    for (int jj = 0; jj < 3; ++jj) {
      const float4 a = *(const float4*)&xr[lane * 4 + jj * 256];
      const float4 w = *(const float4*)(wrow + lane * 4 + jj * 256);
      acc = fmaf(a.x, w.x, acc);
      acc = fmaf(a.y, w.y, acc);
      acc = fmaf(a.z, w.z, acc);
      acc = fmaf(a.w, w.w, acc);
    }
#pragma unroll
    for (int o = 32; o > 0; o >>= 1) acc += __shfl_down(acc, o, 64);
    if (lane == 0) {
      const float nv = acc + b_enc[col];
      sv[s] = nv;
      su[s] = __float_as_uint(nv);
    }
  }
  __syncthreads();

  // pass 2: exact 64th on corrected values
  const unsigned T = kth_largest(4);

  if (tid == 0) basev = 0;
  __syncthreads();
  // compaction pass 1: strictly greater (deterministic order)
  for (int s0 = 0; s0 < c; s0 += 256) {
    const int s = s0 + tid;
    const bool take = (s < c) && (su[s] > T);
    const unsigned long long m = __ballot(take);
    const int wsum = __popcll(m);
    const int wpre = __popcll(m & ((1ull << lane) - 1ull));
    if (lane == 0) woff[wid] = wsum;
    __syncthreads();
    int pre = 0;
    for (int w = 0; w < wid; ++w) pre += woff[w];
    const int tot = woff[0] + woff[1] + woff[2] + woff[3];
    if (take) {
      const int p = basev + pre + wpre;
      tv[p] = sv[s];
      ti[p] = cir[s];
    }
    __syncthreads();
    if (tid == 0) basev += tot;
    __syncthreads();
  }
  // compaction pass 2: ties (== T), earliest slots first
  for (int s0 = 0; s0 < c; s0 += 256) {
    const int s = s0 + tid;
    const bool take = (s < c) && (su[s] == T);
    const unsigned long long m = __ballot(take);
    const int wsum = __popcll(m);
    const int wpre = __popcll(m & ((1ull << lane) - 1ull));
    if (lane == 0) woff[wid] = wsum;
    __syncthreads();
    int pre = 0;
    for (int w = 0; w < wid; ++w) pre += woff[w];
    const int tot = woff[0] + woff[1] + woff[2] + woff[3];
    if (take) {
      const int p = basev + pre + wpre;
      if (p < TOPK) {
        tv[p] = sv[s];
        ti[p] = cir[s];
      }
    }
    __syncthreads();
    if (tid == 0) basev += tot;
    __syncthreads();
  }
  __syncthreads();

  // decode with 4 independent accumulator chains (fixed combine order)
  if (tid < 192) {
    const int d = tid * 4;
    float4 a0 = {0.f, 0.f, 0.f, 0.f}, a1 = a0, a2 = a0, a3 = a0;
#pragma unroll 4
    for (int kk = 0; kk < 16; ++kk) {
      const float4 w0 = *(const float4*)(W_dec + (size_t)ti[kk * 4 + 0] * DIN + d);
      const float4 w1 = *(const float4*)(W_dec + (size_t)ti[kk * 4 + 1] * DIN + d);
      const float4 w2 = *(const float4*)(W_dec + (size_t)ti[kk * 4 + 2] * DIN + d);
      const float4 w3 = *(const float4*)(W_dec + (size_t)ti[kk * 4 + 3] * DIN + d);
      const float v0 = tv[kk * 4 + 0], v1 = tv[kk * 4 + 1];
      const float v2 = tv[kk * 4 + 2], v3 = tv[kk * 4 + 3];
      a0.x = fmaf(v0, w0.x, a0.x); a0.y = fmaf(v0, w0.y, a0.y);
      a0.z = fmaf(v0, w0.z, a0.z); a0.w = fmaf(v0, w0.w, a0.w);
      a1.x = fmaf(v1, w1.x, a1.x); a1.y = fmaf(v1, w1.y, a1.y);
      a1.z = fmaf(v1, w1.z, a1.z); a1.w = fmaf(v1, w1.w, a1.w);
      a2.x = fmaf(v2, w2.x, a2.x); a2.y = fmaf(v2, w2.y, a2.y);
      a2.z = fmaf(v2, w2.z, a2.z); a2.w = fmaf(v2, w2.w, a2.w);
      a3.x = fmaf(v3, w3.x, a3.x); a3.y = fmaf(v3, w3.y, a3.y);
      a3.z = fmaf(v3, w3.z, a3.z); a3.w = fmaf(v3, w3.w, a3.w);
    }
    const float4 bd = *(const float4*)(b_dec + d);
    float4 acc;
    acc.x = bd.x + ((a0.x + a1.x) + (a2.x + a3.x));
    acc.y = bd.y + ((a0.y + a1.y) + (a2.y + a3.y));
    acc.z = bd.z + ((a0.z + a1.z) + (a2.z + a3.z));
    acc.w = bd.w + ((a0.w + a1.w) + (a2.w + a3.w));
    *(float4*)(out + (size_t)row * DIN + d) = acc;
  }
}

// ================= fallback chain (ws too small for Wt) =================
__global__ __launch_bounds__(256) void k_band(const int* __restrict__ cnt,
                                              const float* __restrict__ cand_v,
                                              int* __restrict__ band_cnt,
                                              int* __restrict__ band_list) {
  const int row = blockIdx.x;
  const int tid = threadIdx.x;
  const int lane = tid & 63, wid = tid >> 6;
  const int c = min(cnt[row], CAP);
  __shared__ unsigned su[CAP];
  __shared__ int redI[4];
  const float* cvr = cand_v + (size_t)row * CAP;
  for (int s = tid; s < c; s += 256) su[s] = __float_as_uint(cvr[s]);
  __syncthreads();
  unsigned T = 0u;
  for (int b = 30; b >= 0; --b) {
    const unsigned Tt = T | (1u << b);
    int cg = 0;
    for (int s = tid; s < c; s += 256) cg += (su[s] >= Tt) ? 1 : 0;
#pragma unroll
    for (int o = 32; o > 0; o >>= 1) cg += __shfl_down(cg, o, 64);
    if (lane == 0) redI[wid] = cg;
    __syncthreads();
    const int tot = redI[0] + redI[1] + redI[2] + redI[3];
    if (tot >= TOPK) T = Tt;
    __syncthreads();
  }
  const float Tf = __uint_as_float(T);
  for (int s = tid; s < c; s += 256) {
    const float v = __uint_as_float(su[s]);
    if (v >= Tf - BAND && v <= Tf + BAND) {
      const int p = atomicAdd(band_cnt, 1);
      if (p < BANDCAP) band_list[p] = (row << CAPLOG) + s;
    }
  }
}

__global__ __launch_bounds__(256) void k_refine(const int* __restrict__ band_cnt,
                                                const int* __restrict__ band_list,
                                                const float* __restrict__ x,
                                                const float* __restrict__ b_dec,
                                                const float* __restrict__ W_enc,
                                                const float* __restrict__ b_enc,
                                                float* __restrict__ cand_v,
                                                const int* __restrict__ cand_i) {
  const int i = blockIdx.x * 256 + threadIdx.x;
  const int nb = min(band_cnt[0], BANDCAP);
  if (i >= nb) return;
  const int e = band_list[i];
  const int row = e >> CAPLOG;
  const int s = e & (CAP - 1);
  const int col = cand_i[(size_t)row * CAP + s];
  const float* xr = x + (size_t)row * DIN;
  float acc = 0.f;
  for (int k = 0; k < DIN; ++k)
    acc = fmaf(xr[k] - b_dec[k], W_enc[(size_t)k * DSAE + col], acc);
  cand_v[(size_t)row * CAP + s] = acc + b_enc[col];
}

__global__ __launch_bounds__(256) void k_select(const int* __restrict__ cnt,
                                                const float* __restrict__ cand_v,
                                                const int* __restrict__ cand_i,
                                                float* __restrict__ top_v,
                                                int* __restrict__ top_i) {
  const int row = blockIdx.x;
  const int tid = threadIdx.x;
  const int lane = tid & 63, wid = tid >> 6;
  const int c = min(cnt[row], CAP);
  __shared__ unsigned su[CAP];
  __shared__ float sv[CAP];
  __shared__ int redI[4];
  __shared__ int woff[4];
  __shared__ int basev;
  __shared__ float tv[TOPK];
  __shared__ int ti[TOPK];
  const float* cvr = cand_v + (size_t)row * CAP;
  const int* cir = cand_i + (size_t)row * CAP;
  for (int s = tid; s < c; s += 256) {
    const float v = cvr[s];
    sv[s] = v;
    su[s] = __float_as_uint(v);
  }
  __syncthreads();
  unsigned T = 0u;
  for (int b = 30; b >= 0; --b) {
    const unsigned Tt = T | (1u << b);
    int cg = 0;
    for (int s = tid; s < c; s += 256) cg += (su[s] >= Tt) ? 1 : 0;
#pragma unroll
    for (int o = 32; o > 0; o >>= 1) cg += __shfl_down(cg, o, 64);
    if (lane == 0) redI[wid] = cg;
    __syncthreads();
    const int tot = redI[0] + redI[1] + redI[2] + redI[3];
    if (tot >= TOPK) T = Tt;
    __syncthreads();
  }
  if (tid == 0) basev = 0;
  __syncthreads();
  for (int s0 = 0; s0 < c; s0 += 256) {
    const int s = s0 + tid;
    const bool take = (s < c) && (su[s] > T);
    const unsigned long long m = __ballot(take);
    const int wsum = __popcll(m);
    const int wpre = __popcll(m & ((1ull << lane) - 1ull));
    if (lane == 0) woff[wid] = wsum;
    __syncthreads();
    int pre = 0;
    for (int w = 0; w < wid; ++w) pre += woff[w];
    const int tot = woff[0] + woff[1] + woff[2] + woff[3];
    if (take) {
      const int p = basev + pre + wpre;
      tv[p] = sv[s];
      ti[p] = cir[s];
    }
    __syncthreads();
    if (tid == 0) basev += tot;
    __syncthreads();
  }
  for (int s0 = 0; s0 < c; s0 += 256) {
    const int s = s0 + tid;
    const bool take = (s < c) && (su[s] == T);
    const unsigned long long m = __ballot(take);
    const int wsum = __popcll(m);
    const int wpre = __popcll(m & ((1ull << lane) - 1ull));
    if (lane == 0) woff[wid] = wsum;
    __syncthreads();
    int pre = 0;
    for (int w = 0; w < wid; ++w) pre += woff[w];
    const int tot = woff[0] + woff[1] + woff[2] + woff[3];
    if (take) {
      const int p = basev + pre + wpre;
      if (p < TOPK) {
        tv[p] = sv[s];
        ti[p] = cir[s];
      }
    }
    __syncthreads();
    if (tid == 0) basev += tot;
    __syncthreads();
  }
  if (tid < TOPK) {
    top_v[(size_t)row * TOPK + tid] = tv[tid];
    top_i[(size_t)row * TOPK + tid] = ti[tid];
  }
}

__global__ __launch_bounds__(192) void k_decode(const float* __restrict__ top_v,
                                                const int* __restrict__ top_i,
                                                const float* __restrict__ W_dec,
                                                const float* __restrict__ b_dec,
                                                float* __restrict__ out) {
  const int row = blockIdx.x;
  const int tid = threadIdx.x;
  __shared__ float v[TOPK];
  __shared__ int ix[TOPK];
  if (tid < TOPK) {
    v[tid] = top_v[(size_t)row * TOPK + tid];
    ix[tid] = top_i[(size_t)row * TOPK + tid];
  }
  __syncthreads();
  const int d = tid * 4;
  float4 acc = *(const float4*)(b_dec + d);
#pragma unroll 8
  for (int k = 0; k < TOPK; ++k) {
    const float4 w = *(const float4*)(W_dec + (size_t)ix[k] * DIN + d);
    const float vk = v[k];
    acc.x = fmaf(vk, w.x, acc.x);
    acc.y = fmaf(vk, w.y, acc.y);
    acc.z = fmaf(vk, w.z, acc.z);
    acc.w = fmaf(vk, w.w, acc.w);
  }
  *(float4*)(out + (size_t)row * DIN + d) = acc;
}

extern "C" void kernel_launch(void* const* d_in, const int* in_sizes, int n_in,
                              void* d_out, int out_size, void* d_ws, size_t ws_size,
                              hipStream_t stream) {
  const float* x = (const float*)d_in[0];
  const float* W_enc = (const float*)d_in[1];
  const float* b_enc = (const float*)d_in[2];
  const float* W_dec = (const float*)d_in[3];
  const float* b_dec = (const float*)d_in[4];
  float* out = (float*)d_out;

  char* p = (char*)d_ws;
  auto alloc = [&](size_t bytes) {
    char* r = p;
    p += (bytes + 255) & ~(size_t)255;
    return r;
  };
  float* tau = (float*)alloc((size_t)NTOK * 4);
  int* cnt = (int*)alloc((size_t)NTOK * 4);
  int* band_cnt = (int*)alloc(256);
  int* band_list = (int*)alloc((size_t)BANDCAP * 4);
  float* cand_v = (float*)alloc((size_t)NTOK * CAP * 4);
  int* cand_i = (int*)alloc((size_t)NTOK * CAP * 4);
  float* top_v = (float*)alloc((size_t)NTOK * TOPK * 4);
  int* top_i = (int*)alloc((size_t)NTOK * TOPK * 4);
  ushort* Ah = (ushort*)alloc((size_t)NTOK * DIN * 2);
  ushort* Bth = (ushort*)alloc((size_t)DSAE * DIN * 2);
  float* Wt = (float*)alloc((size_t)DSAE * DIN * 4);
  const bool fastT = ((size_t)(p - (char*)d_ws) <= ws_size);

  const int nconv = (DIN / 32) * (DSAE / 128);  // 6144
  hipLaunchKernelGGL(k_pre, dim3(nconv + NTOK), dim3(256), 0, stream,
                     x, b_dec, Ah, tau, cnt, band_cnt, W_enc, Wt, Bth, (int)fastT);
  hipLaunchKernelGGL(k_gemm_mfma, dim3((NTOK / GBM) * (DSAE / GBN)), dim3(512), 0, stream,
                     Ah, Bth, b_enc, tau, cnt, cand_v, cand_i);
  if (fastT) {
    hipLaunchKernelGGL(k_selref, dim3(NTOK), dim3(256), 0, stream,
                       cnt, cand_v, cand_i, x, Wt, b_enc, W_dec, b_dec, out);
  } else {
    hipLaunchKernelGGL(k_band, dim3(NTOK), dim3(256), 0, stream, cnt, cand_v, band_cnt, band_list);
    hipLaunchKernelGGL(k_refine, dim3(BANDCAP / 256), dim3(256), 0, stream,
                       band_cnt, band_list, x, b_dec, W_enc, b_enc, cand_v, cand_i);
    hipLaunchKernelGGL(k_select, dim3(NTOK), dim3(256), 0, stream, cnt, cand_v, cand_i, top_v, top_i);
    hipLaunchKernelGGL(k_decode, dim3(NTOK), dim3(192), 0, stream, top_v, top_i, W_dec, b_dec, out);
  }
}